// Round 1
// baseline (4158.922 us; speedup 1.0000x reference)
//
#include <hip/hip_runtime.h>
#include <hip/hip_bf16.h>
#include <stdint.h>

// LoopMoE on MI355X: router (fp32) -> compact per-expert lists -> bf16 MFMA
// grouped GEMM1 (SwiGLU fused) -> bf16 MFMA grouped GEMM2 (scatter-add fp32).
// m97-style 128x128xBK32 tiles, global_load_lds width-16 staging.

#define T_TOK 8192
#define HID   2048
#define INTER 4096
#define NEXP  8
#define CAP   16384   // total assignments = T_TOK * topk

typedef float  f32x4  __attribute__((ext_vector_type(4)));
typedef __bf16 bf16x8 __attribute__((ext_vector_type(8)));
typedef unsigned short ushort8 __attribute__((ext_vector_type(8)));

typedef const unsigned int __attribute__((address_space(1)))* gptr_t;
typedef unsigned int       __attribute__((address_space(3)))* lptr_t;

__device__ __forceinline__ void gload16(const void* g, void* l) {
  // async global->LDS, 16B per lane; LDS dest = wave-uniform base + lane*16
  __builtin_amdgcn_global_load_lds((gptr_t)g, (lptr_t)l, 16, 0, 0);
}

__device__ __forceinline__ unsigned short f2bf(float f) {
  unsigned int u = __builtin_bit_cast(unsigned int, f);
  unsigned int r = (u + 0x7fffu + ((u >> 16) & 1u)) >> 16;  // RNE
  return (unsigned short)r;
}

// ---------------- fp32 -> bf16 conversion (vectorized, grid-stride) --------
__global__ __launch_bounds__(256) void cvt_kernel(const float* __restrict__ in,
                                                  unsigned short* __restrict__ out,
                                                  long n8) {
  long stride = (long)gridDim.x * 256;
  for (long i = (long)blockIdx.x * 256 + threadIdx.x; i < n8; i += stride) {
    const f32x4* p = (const f32x4*)(in + i * 8);
    f32x4 a = p[0], b = p[1];
    ushort8 o;
    o[0] = f2bf(a[0]); o[1] = f2bf(a[1]); o[2] = f2bf(a[2]); o[3] = f2bf(a[3]);
    o[4] = f2bf(b[0]); o[5] = f2bf(b[1]); o[6] = f2bf(b[2]); o[7] = f2bf(b[3]);
    *(ushort8*)(out + i * 8) = o;
  }
}

// ---------------- router: fp32 logits, softmax, top-2 ----------------------
__global__ __launch_bounds__(64) void router_kernel(const float* __restrict__ x,
                                                    const float* __restrict__ rw,
                                                    int* __restrict__ tokexp,
                                                    float* __restrict__ tokwt,
                                                    int* __restrict__ counts) {
  int t = blockIdx.x, lane = threadIdx.x;
  const float* xrow = x + (size_t)t * HID;
  float xr[32];
#pragma unroll
  for (int i = 0; i < 32; i++) xr[i] = xrow[lane + 64 * i];
  float lg[NEXP];
#pragma unroll
  for (int e = 0; e < NEXP; e++) {
    const float* r = rw + e * HID;
    float d = 0.f;
#pragma unroll
    for (int i = 0; i < 32; i++) d = fmaf(xr[i], r[lane + 64 * i], d);
#pragma unroll
    for (int s = 32; s; s >>= 1) d += __shfl_xor(d, s);
    lg[e] = d;
  }
  if (lane == 0) {
    float mx = lg[0];
    for (int e = 1; e < NEXP; e++) mx = fmaxf(mx, lg[e]);
    float p[NEXP], sum = 0.f;
    for (int e = 0; e < NEXP; e++) { p[e] = expf(lg[e] - mx); sum += p[e]; }
    int e0 = 0; float b0 = p[0];
    for (int e = 1; e < NEXP; e++) if (p[e] > b0) { b0 = p[e]; e0 = e; }
    int e1 = -1; float b1 = -1.f;
    for (int e = 0; e < NEXP; e++) if (e != e0 && p[e] > b1) { b1 = p[e]; e1 = e; }
    float inv = 1.f / sum;
    tokexp[2 * t] = e0; tokexp[2 * t + 1] = e1;
    tokwt[2 * t] = b0 * inv; tokwt[2 * t + 1] = b1 * inv;
    atomicAdd(&counts[e0], 1);
    atomicAdd(&counts[e1], 1);
  }
}

// ---------------- scan + placement -----------------------------------------
__global__ void scan_kernel(const int* __restrict__ counts, int* __restrict__ offsets,
                            int* __restrict__ cursors) {
  if (threadIdx.x == 0) {
    int acc = 0;
    for (int e = 0; e < NEXP; e++) { offsets[e] = acc; cursors[e] = acc; acc += counts[e]; }
  }
}

__global__ __launch_bounds__(256) void place_kernel(const int* __restrict__ tokexp,
                                                    const float* __restrict__ tokwt,
                                                    int* __restrict__ cursors,
                                                    int* __restrict__ rowtok,
                                                    float* __restrict__ rowwt) {
  int a = blockIdx.x * 256 + threadIdx.x;
  if (a >= 2 * T_TOK) return;
  int e = tokexp[a];
  int pos = atomicAdd(&cursors[e], 1);
  rowtok[pos] = a >> 1;
  rowwt[pos] = tokwt[a];
}

// ---------------- GEMM1: h = silu(x@Wg^T) * (x@Wu^T), gathered rows --------
__global__ __launch_bounds__(256) void gemm1_kernel(
    const unsigned short* __restrict__ xb, const unsigned short* __restrict__ w1b,
    unsigned short* __restrict__ hbuf, const int* __restrict__ rowtok,
    const int* __restrict__ counts, const int* __restrict__ offsets) {
  int e = blockIdx.z;
  int cnt = counts[e];
  int m0 = blockIdx.x * 128;
  if (m0 >= cnt) return;
  int n0 = blockIdx.y * 128;
  int off = offsets[e];

  __shared__ unsigned short sA[128 * 32];
  __shared__ unsigned short sBg[128 * 32];
  __shared__ unsigned short sBu[128 * 32];
  __shared__ unsigned int stok[128];

  int tid = threadIdx.x;
  if (tid < 128) {
    int r = m0 + tid; if (r > cnt - 1) r = cnt - 1;
    stok[tid] = (unsigned)rowtok[off + r] * (HID * 2);
  }
  __syncthreads();

  int slot0 = tid, slot1 = tid + 256;           // 512 x 16B slots per matrix
  const char* xc = (const char*)xb;
  const char* ga0 = xc + stok[slot0 >> 2] + (slot0 & 3) * 16;
  const char* ga1 = xc + stok[slot1 >> 2] + (slot1 & 3) * 16;
  const char* w1e = (const char*)w1b + (size_t)e * (2 * INTER) * HID * 2;
  const char* gg0 = w1e + (size_t)(n0 + (slot0 >> 2)) * (HID * 2) + (slot0 & 3) * 16;
  const char* gg1 = w1e + (size_t)(n0 + (slot1 >> 2)) * (HID * 2) + (slot1 & 3) * 16;
  const char* gu0 = gg0 + (size_t)INTER * HID * 2;
  const char* gu1 = gg1 + (size_t)INTER * HID * 2;
  char* lA0 = (char*)sA + slot0 * 16;  char* lA1 = (char*)sA + slot1 * 16;
  char* lG0 = (char*)sBg + slot0 * 16; char* lG1 = (char*)sBg + slot1 * 16;
  char* lU0 = (char*)sBu + slot0 * 16; char* lU1 = (char*)sBu + slot1 * 16;

  int lane = tid & 63, wid = tid >> 6;
  int wrow = (wid >> 1) * 64, wcol = (wid & 1) * 64;
  int fr = lane & 15, fq = lane >> 4;

  f32x4 accg[4][4] = {};
  f32x4 accu[4][4] = {};

  for (int kk = 0; kk < HID; kk += 32) {
    int kb = kk * 2;
    gload16(ga0 + kb, lA0); gload16(ga1 + kb, lA1);
    gload16(gg0 + kb, lG0); gload16(gg1 + kb, lG1);
    gload16(gu0 + kb, lU0); gload16(gu1 + kb, lU1);
    __syncthreads();   // compiler drains vmcnt before s_barrier
    bf16x8 a[4], bg[4], bu[4];
#pragma unroll
    for (int m = 0; m < 4; m++)
      a[m] = *(const bf16x8*)(sA + (wrow + m * 16 + fr) * 32 + fq * 8);
#pragma unroll
    for (int n = 0; n < 4; n++) {
      bg[n] = *(const bf16x8*)(sBg + (wcol + n * 16 + fr) * 32 + fq * 8);
      bu[n] = *(const bf16x8*)(sBu + (wcol + n * 16 + fr) * 32 + fq * 8);
    }
#pragma unroll
    for (int m = 0; m < 4; m++)
#pragma unroll
      for (int n = 0; n < 4; n++) {
        accg[m][n] = __builtin_amdgcn_mfma_f32_16x16x32_bf16(a[m], bg[n], accg[m][n], 0, 0, 0);
        accu[m][n] = __builtin_amdgcn_mfma_f32_16x16x32_bf16(a[m], bu[n], accu[m][n], 0, 0, 0);
      }
    __syncthreads();
  }

  // epilogue: h = up * silu(gate); C/D map col=lane&15, row=(lane>>4)*4+reg
#pragma unroll
  for (int m = 0; m < 4; m++) {
#pragma unroll
    for (int r = 0; r < 4; r++) {
      int row = wrow + m * 16 + fq * 4 + r;
      int grow = m0 + row;
      if (grow >= cnt) continue;
      size_t hb = (size_t)(off + grow) * INTER;
#pragma unroll
      for (int n = 0; n < 4; n++) {
        float g = accg[m][n][r];
        float u = accu[m][n][r];
        float hv = u * g / (1.f + __expf(-g));
        hbuf[hb + n0 + wcol + n * 16 + fr] = f2bf(hv);
      }
    }
  }
}

// ---------------- GEMM2: out[tok] += wt * (h @ W2^T) -----------------------
__global__ __launch_bounds__(256) void gemm2_kernel(
    const unsigned short* __restrict__ hbuf, const unsigned short* __restrict__ w2b,
    const int* __restrict__ rowtok, const float* __restrict__ rowwt,
    const int* __restrict__ counts, const int* __restrict__ offsets,
    float* __restrict__ out) {
  int e = blockIdx.z;
  int cnt = counts[e];
  int m0 = blockIdx.x * 128;
  if (m0 >= cnt) return;
  int n0 = blockIdx.y * 128;
  int off = offsets[e];

  __shared__ unsigned short sA[128 * 32];
  __shared__ unsigned short sB[128 * 32];

  int tid = threadIdx.x;
  int slot0 = tid, slot1 = tid + 256;
  int ar0 = m0 + (slot0 >> 2); if (ar0 > cnt - 1) ar0 = cnt - 1;
  int ar1 = m0 + (slot1 >> 2); if (ar1 > cnt - 1) ar1 = cnt - 1;
  const char* hc = (const char*)hbuf;
  const char* ga0 = hc + (size_t)(off + ar0) * (INTER * 2) + (slot0 & 3) * 16;
  const char* ga1 = hc + (size_t)(off + ar1) * (INTER * 2) + (slot1 & 3) * 16;
  const char* w2e = (const char*)w2b + (size_t)e * HID * INTER * 2;
  const char* gb0 = w2e + (size_t)(n0 + (slot0 >> 2)) * (INTER * 2) + (slot0 & 3) * 16;
  const char* gb1 = w2e + (size_t)(n0 + (slot1 >> 2)) * (INTER * 2) + (slot1 & 3) * 16;
  char* lA0 = (char*)sA + slot0 * 16; char* lA1 = (char*)sA + slot1 * 16;
  char* lB0 = (char*)sB + slot0 * 16; char* lB1 = (char*)sB + slot1 * 16;

  int lane = tid & 63, wid = tid >> 6;
  int wrow = (wid >> 1) * 64, wcol = (wid & 1) * 64;
  int fr = lane & 15, fq = lane >> 4;

  f32x4 acc[4][4] = {};

  for (int kk = 0; kk < INTER; kk += 32) {
    int kb = kk * 2;
    gload16(ga0 + kb, lA0); gload16(ga1 + kb, lA1);
    gload16(gb0 + kb, lB0); gload16(gb1 + kb, lB1);
    __syncthreads();
    bf16x8 a[4], b[4];
#pragma unroll
    for (int m = 0; m < 4; m++)
      a[m] = *(const bf16x8*)(sA + (wrow + m * 16 + fr) * 32 + fq * 8);
#pragma unroll
    for (int n = 0; n < 4; n++)
      b[n] = *(const bf16x8*)(sB + (wcol + n * 16 + fr) * 32 + fq * 8);
#pragma unroll
    for (int m = 0; m < 4; m++)
#pragma unroll
      for (int n = 0; n < 4; n++)
        acc[m][n] = __builtin_amdgcn_mfma_f32_16x16x32_bf16(a[m], b[n], acc[m][n], 0, 0, 0);
    __syncthreads();
  }

#pragma unroll
  for (int m = 0; m < 4; m++) {
#pragma unroll
    for (int r = 0; r < 4; r++) {
      int grow = m0 + wrow + m * 16 + fq * 4 + r;
      if (grow >= cnt) continue;
      int tok = rowtok[off + grow];
      float wt = rowwt[off + grow];
      float* orow = out + (size_t)tok * HID + n0 + wcol;
#pragma unroll
      for (int n = 0; n < 4; n++)
        atomicAdd(orow + n * 16 + fr, acc[m][n][r] * wt);
    }
  }
}

// ---------------- host launch ----------------------------------------------
extern "C" void kernel_launch(void* const* d_in, const int* in_sizes, int n_in,
                              void* d_out, int out_size, void* d_ws, size_t ws_size,
                              hipStream_t stream) {
  const float* x  = (const float*)d_in[0];
  const float* w1 = (const float*)d_in[1];
  const float* w2 = (const float*)d_in[2];
  const float* rw = (const float*)d_in[3];

  char* ws = (char*)d_ws;
  size_t o = 0;
  auto alloc = [&](size_t bytes) {
    char* p = ws + o;
    o += (bytes + 255) & ~(size_t)255;
    return p;
  };
  unsigned short* xb   = (unsigned short*)alloc((size_t)T_TOK * HID * 2);
  unsigned short* w1b  = (unsigned short*)alloc((size_t)NEXP * 2 * INTER * HID * 2);
  unsigned short* w2b  = (unsigned short*)alloc((size_t)NEXP * HID * INTER * 2);
  unsigned short* hbuf = (unsigned short*)alloc((size_t)CAP * INTER * 2);
  int*   rowtok = (int*)alloc((size_t)CAP * 4);
  float* rowwt  = (float*)alloc((size_t)CAP * 4);
  int*   tokexp = (int*)alloc((size_t)2 * T_TOK * 4);
  float* tokwt  = (float*)alloc((size_t)2 * T_TOK * 4);
  int*   ctrl   = (int*)alloc(32 * 4);
  int* counts = ctrl; int* offsets = ctrl + 8; int* cursors = ctrl + 16;
  if (o > ws_size) return;  // ws too small: bail cleanly (output stays poisoned)

  hipMemsetAsync(ctrl, 0, 32 * 4, stream);
  hipMemsetAsync(d_out, 0, (size_t)out_size * 4, stream);

  cvt_kernel<<<2048, 256, 0, stream>>>(x,  xb,  (long)T_TOK * HID / 8);
  cvt_kernel<<<4096, 256, 0, stream>>>(w1, w1b, (long)NEXP * 2 * INTER * HID / 8);
  cvt_kernel<<<4096, 256, 0, stream>>>(w2, w2b, (long)NEXP * HID * INTER / 8);

  router_kernel<<<T_TOK, 64, 0, stream>>>(x, rw, tokexp, tokwt, counts);
  scan_kernel<<<1, 64, 0, stream>>>(counts, offsets, cursors);
  place_kernel<<<(2 * T_TOK) / 256, 256, 0, stream>>>(tokexp, tokwt, cursors, rowtok, rowwt);

  gemm1_kernel<<<dim3(T_TOK / 128, INTER / 128, NEXP), 256, 0, stream>>>(
      xb, w1b, hbuf, rowtok, counts, offsets);
  gemm2_kernel<<<dim3(T_TOK / 128, HID / 128, NEXP), 256, 0, stream>>>(
      hbuf, w2b, rowtok, rowwt, counts, offsets, (float*)d_out);
}

// Round 3
// 3732.162 us; speedup vs baseline: 1.1143x; 1.1143x over previous
//
#include <hip/hip_runtime.h>
#include <hip/hip_bf16.h>
#include <stdint.h>

// LoopMoE on MI355X: router (fp32) -> compact per-expert lists -> bf16 MFMA
// grouped GEMM1 (SwiGLU fused) -> bf16 MFMA grouped GEMM2 (scatter-add fp32).
// R2 (resubmitted R3; R2 bench lost to GPU timeout): BK=64 (128B LDS rows) +
// ((row&7)<<4) XOR swizzle applied BOTH on the pre-swizzled global_load_lds
// source and on ds_read_b128 fragment reads (guide T2 + rule #21). Fixes the
// 8-way bank conflict that capped R1 at MfmaUtil 10%.

#define T_TOK 8192
#define HID   2048
#define INTER 4096
#define NEXP  8
#define CAP   16384   // total assignments = T_TOK * topk

typedef float  f32x4  __attribute__((ext_vector_type(4)));
typedef __bf16 bf16x8 __attribute__((ext_vector_type(8)));
typedef unsigned short ushort8 __attribute__((ext_vector_type(8)));

typedef const unsigned int __attribute__((address_space(1)))* gptr_t;
typedef unsigned int       __attribute__((address_space(3)))* lptr_t;

__device__ __forceinline__ void gload16(const void* g, void* l) {
  // async global->LDS, 16B/lane; LDS dest = wave-uniform base + lane*16
  __builtin_amdgcn_global_load_lds((gptr_t)g, (lptr_t)l, 16, 0, 0);
}

__device__ __forceinline__ unsigned short f2bf(float f) {
  unsigned int u = __builtin_bit_cast(unsigned int, f);
  unsigned int r = (u + 0x7fffu + ((u >> 16) & 1u)) >> 16;  // RNE
  return (unsigned short)r;
}

// ---------------- fp32 -> bf16 conversion (vectorized, grid-stride) --------
__global__ __launch_bounds__(256) void cvt_kernel(const float* __restrict__ in,
                                                  unsigned short* __restrict__ out,
                                                  long n8) {
  long stride = (long)gridDim.x * 256;
  for (long i = (long)blockIdx.x * 256 + threadIdx.x; i < n8; i += stride) {
    const f32x4* p = (const f32x4*)(in + i * 8);
    f32x4 a = p[0], b = p[1];
    ushort8 o;
    o[0] = f2bf(a[0]); o[1] = f2bf(a[1]); o[2] = f2bf(a[2]); o[3] = f2bf(a[3]);
    o[4] = f2bf(b[0]); o[5] = f2bf(b[1]); o[6] = f2bf(b[2]); o[7] = f2bf(b[3]);
    *(ushort8*)(out + i * 8) = o;
  }
}

// ---------------- router: fp32 logits, softmax, top-2 ----------------------
__global__ __launch_bounds__(64) void router_kernel(const float* __restrict__ x,
                                                    const float* __restrict__ rw,
                                                    int* __restrict__ tokexp,
                                                    float* __restrict__ tokwt,
                                                    int* __restrict__ counts) {
  int t = blockIdx.x, lane = threadIdx.x;
  const float* xrow = x + (size_t)t * HID;
  float xr[32];
#pragma unroll
  for (int i = 0; i < 32; i++) xr[i] = xrow[lane + 64 * i];
  float lg[NEXP];
#pragma unroll
  for (int e = 0; e < NEXP; e++) {
    const float* r = rw + e * HID;
    float d = 0.f;
#pragma unroll
    for (int i = 0; i < 32; i++) d = fmaf(xr[i], r[lane + 64 * i], d);
#pragma unroll
    for (int s = 32; s; s >>= 1) d += __shfl_xor(d, s);
    lg[e] = d;
  }
  if (lane == 0) {
    float mx = lg[0];
    for (int e = 1; e < NEXP; e++) mx = fmaxf(mx, lg[e]);
    float p[NEXP], sum = 0.f;
    for (int e = 0; e < NEXP; e++) { p[e] = expf(lg[e] - mx); sum += p[e]; }
    int e0 = 0; float b0 = p[0];
    for (int e = 1; e < NEXP; e++) if (p[e] > b0) { b0 = p[e]; e0 = e; }
    int e1 = -1; float b1 = -1.f;
    for (int e = 0; e < NEXP; e++) if (e != e0 && p[e] > b1) { b1 = p[e]; e1 = e; }
    float inv = 1.f / sum;
    tokexp[2 * t] = e0; tokexp[2 * t + 1] = e1;
    tokwt[2 * t] = b0 * inv; tokwt[2 * t + 1] = b1 * inv;
    atomicAdd(&counts[e0], 1);
    atomicAdd(&counts[e1], 1);
  }
}

// ---------------- scan + placement -----------------------------------------
__global__ void scan_kernel(const int* __restrict__ counts, int* __restrict__ offsets,
                            int* __restrict__ cursors) {
  if (threadIdx.x == 0) {
    int acc = 0;
    for (int e = 0; e < NEXP; e++) { offsets[e] = acc; cursors[e] = acc; acc += counts[e]; }
  }
}

__global__ __launch_bounds__(256) void place_kernel(const int* __restrict__ tokexp,
                                                    const float* __restrict__ tokwt,
                                                    int* __restrict__ cursors,
                                                    int* __restrict__ rowtok,
                                                    float* __restrict__ rowwt) {
  int a = blockIdx.x * 256 + threadIdx.x;
  if (a >= 2 * T_TOK) return;
  int e = tokexp[a];
  int pos = atomicAdd(&cursors[e], 1);
  rowtok[pos] = a >> 1;
  rowwt[pos] = tokwt[a];
}

// ---------------- GEMM1: h = silu(x@Wg^T) * (x@Wu^T), gathered rows --------
// BK=64: LDS row = 128B = 8 x 16B chunks; swizzle chunk ^= (row&7).
__global__ __launch_bounds__(256) void gemm1_kernel(
    const unsigned short* __restrict__ xb, const unsigned short* __restrict__ w1b,
    unsigned short* __restrict__ hbuf, const int* __restrict__ rowtok,
    const int* __restrict__ counts, const int* __restrict__ offsets) {
  int e = blockIdx.z;
  int cnt = counts[e];
  int m0 = blockIdx.x * 128;
  if (m0 >= cnt) return;
  int n0 = blockIdx.y * 128;
  int off = offsets[e];

  __shared__ unsigned short sA[128 * 64];   // 16 KB each
  __shared__ unsigned short sBg[128 * 64];
  __shared__ unsigned short sBu[128 * 64];
  __shared__ unsigned int stok[128];

  int tid = threadIdx.x;
  if (tid < 128) {
    int r = m0 + tid; if (r > cnt - 1) r = cnt - 1;
    stok[tid] = (unsigned)rowtok[off + r] * (HID * 2);
  }
  __syncthreads();

  // staging: 1024 slots/matrix of 16B; thread owns slots tid+256j, j=0..3.
  // slot -> row = slot>>3, chunk = slot&7; global chunk = chunk ^ (row&7).
  int srow0 = tid >> 3;
  int schunk = tid & 7;
  unsigned aoff[4], boff[4];
#pragma unroll
  for (int j = 0; j < 4; j++) {
    int r = srow0 + 32 * j;
    int c = schunk ^ (r & 7);
    aoff[j] = stok[r] + c * 16;
    boff[j] = (unsigned)(n0 + r) * (HID * 2) + c * 16;
  }
  const char* xc  = (const char*)xb;
  const char* w1g = (const char*)w1b + (size_t)e * (2 * INTER) * HID * 2;
  const char* w1u = w1g + (size_t)INTER * HID * 2;
  char* lA = (char*)sA  + tid * 16;
  char* lG = (char*)sBg + tid * 16;
  char* lU = (char*)sBu + tid * 16;

  int lane = tid & 63, wid = tid >> 6;
  int wrow = (wid >> 1) * 64, wcol = (wid & 1) * 64;
  int fr = lane & 15, fq = lane >> 4;
  int sw = fr & 7;
  // fragment read (ushort units): row*64 + ((kk2*4+fq)^sw)*8
  int c0 = (fq ^ sw) * 8;
  int c1 = ((fq + 4) ^ sw) * 8;

  f32x4 accg[4][4] = {};
  f32x4 accu[4][4] = {};

  for (int kb = 0; kb < HID * 2; kb += 128) {
#pragma unroll
    for (int j = 0; j < 4; j++) gload16(xc  + aoff[j] + kb, lA + j * 4096);
#pragma unroll
    for (int j = 0; j < 4; j++) gload16(w1g + boff[j] + kb, lG + j * 4096);
#pragma unroll
    for (int j = 0; j < 4; j++) gload16(w1u + boff[j] + kb, lU + j * 4096);
    __syncthreads();   // compiler drains vmcnt before s_barrier
#pragma unroll
    for (int kk2 = 0; kk2 < 2; kk2++) {
      int co = kk2 ? c1 : c0;
      bf16x8 a[4];
#pragma unroll
      for (int m = 0; m < 4; m++)
        a[m] = *(const bf16x8*)(sA + (wrow + m * 16 + fr) * 64 + co);
#pragma unroll
      for (int n = 0; n < 4; n++) {
        bf16x8 bg = *(const bf16x8*)(sBg + (wcol + n * 16 + fr) * 64 + co);
        bf16x8 bu = *(const bf16x8*)(sBu + (wcol + n * 16 + fr) * 64 + co);
#pragma unroll
        for (int m = 0; m < 4; m++) {
          accg[m][n] = __builtin_amdgcn_mfma_f32_16x16x32_bf16(a[m], bg, accg[m][n], 0, 0, 0);
          accu[m][n] = __builtin_amdgcn_mfma_f32_16x16x32_bf16(a[m], bu, accu[m][n], 0, 0, 0);
        }
      }
    }
    __syncthreads();
  }

  // epilogue: h = up * silu(gate); C/D map col=lane&15, row=(lane>>4)*4+reg
#pragma unroll
  for (int m = 0; m < 4; m++) {
#pragma unroll
    for (int r = 0; r < 4; r++) {
      int row = wrow + m * 16 + fq * 4 + r;
      int grow = m0 + row;
      if (grow >= cnt) continue;
      size_t hb = (size_t)(off + grow) * INTER;
#pragma unroll
      for (int n = 0; n < 4; n++) {
        float g = accg[m][n][r];
        float u = accu[m][n][r];
        float hv = u * g / (1.f + __expf(-g));
        hbuf[hb + n0 + wcol + n * 16 + fr] = f2bf(hv);
      }
    }
  }
}

// ---------------- GEMM2: out[tok] += wt * (h @ W2^T) -----------------------
__global__ __launch_bounds__(256) void gemm2_kernel(
    const unsigned short* __restrict__ hbuf, const unsigned short* __restrict__ w2b,
    const int* __restrict__ rowtok, const float* __restrict__ rowwt,
    const int* __restrict__ counts, const int* __restrict__ offsets,
    float* __restrict__ out) {
  int e = blockIdx.z;
  int cnt = counts[e];
  int m0 = blockIdx.x * 128;
  if (m0 >= cnt) return;
  int n0 = blockIdx.y * 128;
  int off = offsets[e];

  __shared__ unsigned short sA[128 * 64];
  __shared__ unsigned short sB[128 * 64];

  int tid = threadIdx.x;
  int srow0 = tid >> 3;
  int schunk = tid & 7;
  unsigned aoff[4], boff[4];
#pragma unroll
  for (int j = 0; j < 4; j++) {
    int r = srow0 + 32 * j;
    int c = schunk ^ (r & 7);
    int ar = m0 + r; if (ar > cnt - 1) ar = cnt - 1;
    aoff[j] = (unsigned)(off + ar) * (INTER * 2) + c * 16;
    boff[j] = (unsigned)(n0 + r) * (INTER * 2) + c * 16;
  }
  const char* hc  = (const char*)hbuf;
  const char* w2e = (const char*)w2b + (size_t)e * HID * INTER * 2;
  char* lA = (char*)sA + tid * 16;
  char* lB = (char*)sB + tid * 16;

  int lane = tid & 63, wid = tid >> 6;
  int wrow = (wid >> 1) * 64, wcol = (wid & 1) * 64;
  int fr = lane & 15, fq = lane >> 4;
  int sw = fr & 7;
  int c0 = (fq ^ sw) * 8;
  int c1 = ((fq + 4) ^ sw) * 8;

  f32x4 acc[4][4] = {};

  for (int kb = 0; kb < INTER * 2; kb += 128) {
#pragma unroll
    for (int j = 0; j < 4; j++) gload16(hc  + aoff[j] + kb, lA + j * 4096);
#pragma unroll
    for (int j = 0; j < 4; j++) gload16(w2e + boff[j] + kb, lB + j * 4096);
    __syncthreads();
#pragma unroll
    for (int kk2 = 0; kk2 < 2; kk2++) {
      int co = kk2 ? c1 : c0;
      bf16x8 a[4];
#pragma unroll
      for (int m = 0; m < 4; m++)
        a[m] = *(const bf16x8*)(sA + (wrow + m * 16 + fr) * 64 + co);
#pragma unroll
      for (int n = 0; n < 4; n++) {
        bf16x8 b = *(const bf16x8*)(sB + (wcol + n * 16 + fr) * 64 + co);
#pragma unroll
        for (int m = 0; m < 4; m++)
          acc[m][n] = __builtin_amdgcn_mfma_f32_16x16x32_bf16(a[m], b, acc[m][n], 0, 0, 0);
      }
    }
    __syncthreads();
  }

#pragma unroll
  for (int m = 0; m < 4; m++) {
#pragma unroll
    for (int r = 0; r < 4; r++) {
      int grow = m0 + wrow + m * 16 + fq * 4 + r;
      if (grow >= cnt) continue;
      int tok = rowtok[off + grow];
      float wt = rowwt[off + grow];
      float* orow = out + (size_t)tok * HID + n0 + wcol;
#pragma unroll
      for (int n = 0; n < 4; n++)
        atomicAdd(orow + n * 16 + fr, acc[m][n][r] * wt);
    }
  }
}

// ---------------- host launch ----------------------------------------------
extern "C" void kernel_launch(void* const* d_in, const int* in_sizes, int n_in,
                              void* d_out, int out_size, void* d_ws, size_t ws_size,
                              hipStream_t stream) {
  const float* x  = (const float*)d_in[0];
  const float* w1 = (const float*)d_in[1];
  const float* w2 = (const float*)d_in[2];
  const float* rw = (const float*)d_in[3];

  char* ws = (char*)d_ws;
  size_t o = 0;
  auto alloc = [&](size_t bytes) {
    char* p = ws + o;
    o += (bytes + 255) & ~(size_t)255;
    return p;
  };
  unsigned short* xb   = (unsigned short*)alloc((size_t)T_TOK * HID * 2);
  unsigned short* w1b  = (unsigned short*)alloc((size_t)NEXP * 2 * INTER * HID * 2);
  unsigned short* w2b  = (unsigned short*)alloc((size_t)NEXP * HID * INTER * 2);
  unsigned short* hbuf = (unsigned short*)alloc((size_t)CAP * INTER * 2);
  int*   rowtok = (int*)alloc((size_t)CAP * 4);
  float* rowwt  = (float*)alloc((size_t)CAP * 4);
  int*   tokexp = (int*)alloc((size_t)2 * T_TOK * 4);
  float* tokwt  = (float*)alloc((size_t)2 * T_TOK * 4);
  int*   ctrl   = (int*)alloc(32 * 4);
  int* counts = ctrl; int* offsets = ctrl + 8; int* cursors = ctrl + 16;
  if (o > ws_size) return;  // ws too small: bail cleanly (output stays poisoned)

  hipMemsetAsync(ctrl, 0, 32 * 4, stream);
  hipMemsetAsync(d_out, 0, (size_t)out_size * 4, stream);

  cvt_kernel<<<2048, 256, 0, stream>>>(x,  xb,  (long)T_TOK * HID / 8);
  cvt_kernel<<<4096, 256, 0, stream>>>(w1, w1b, (long)NEXP * 2 * INTER * HID / 8);
  cvt_kernel<<<4096, 256, 0, stream>>>(w2, w2b, (long)NEXP * HID * INTER / 8);

  router_kernel<<<T_TOK, 64, 0, stream>>>(x, rw, tokexp, tokwt, counts);
  scan_kernel<<<1, 64, 0, stream>>>(counts, offsets, cursors);
  place_kernel<<<(2 * T_TOK) / 256, 256, 0, stream>>>(tokexp, tokwt, cursors, rowtok, rowwt);

  gemm1_kernel<<<dim3(T_TOK / 128, INTER / 128, NEXP), 256, 0, stream>>>(
      xb, w1b, hbuf, rowtok, counts, offsets);
  gemm2_kernel<<<dim3(T_TOK / 128, HID / 128, NEXP), 256, 0, stream>>>(
      hbuf, w2b, rowtok, rowwt, counts, offsets, (float*)d_out);
}

// Round 8
// 2782.648 us; speedup vs baseline: 1.4946x; 1.3412x over previous
//
#include <hip/hip_runtime.h>
#include <hip/hip_bf16.h>
#include <stdint.h>

// LoopMoE on MI355X: router (fp32) -> compact per-expert lists -> bf16 MFMA
// grouped GEMM1 (SwiGLU fused) -> bf16 MFMA grouped GEMM2 (scatter-add fp32).
// R4 (resubmitted R8; R4-R7 benches lost to GPU timeouts): gemm1 was
// register-occupancy-bound (152 VGPR + 128 AGPR dual-acc = 280 regs > 256 ->
// 1 wave/SIMD, no latency hiding, MfmaUtil 11.7%). Restructure: 512 threads /
// 8 waves, gate-vs-up split across wave halves (64 AGPR each), fp32 LDS
// exchange for the SwiGLU epilogue. BK=64 + XOR swizzle kept (R3 zeroed bank
// conflicts). gemm2 unchanged (control).

#define T_TOK 8192
#define HID   2048
#define INTER 4096
#define NEXP  8
#define CAP   16384   // total assignments = T_TOK * topk

typedef float  f32x4  __attribute__((ext_vector_type(4)));
typedef __bf16 bf16x8 __attribute__((ext_vector_type(8)));
typedef unsigned short ushort8 __attribute__((ext_vector_type(8)));

typedef const unsigned int __attribute__((address_space(1)))* gptr_t;
typedef unsigned int       __attribute__((address_space(3)))* lptr_t;

__device__ __forceinline__ void gload16(const void* g, void* l) {
  // async global->LDS, 16B/lane; LDS dest = wave-uniform base + lane*16
  __builtin_amdgcn_global_load_lds((gptr_t)g, (lptr_t)l, 16, 0, 0);
}

__device__ __forceinline__ unsigned short f2bf(float f) {
  unsigned int u = __builtin_bit_cast(unsigned int, f);
  unsigned int r = (u + 0x7fffu + ((u >> 16) & 1u)) >> 16;  // RNE
  return (unsigned short)r;
}

// ---------------- fp32 -> bf16 conversion (vectorized, grid-stride) --------
__global__ __launch_bounds__(256) void cvt_kernel(const float* __restrict__ in,
                                                  unsigned short* __restrict__ out,
                                                  long n8) {
  long stride = (long)gridDim.x * 256;
  for (long i = (long)blockIdx.x * 256 + threadIdx.x; i < n8; i += stride) {
    const f32x4* p = (const f32x4*)(in + i * 8);
    f32x4 a = p[0], b = p[1];
    ushort8 o;
    o[0] = f2bf(a[0]); o[1] = f2bf(a[1]); o[2] = f2bf(a[2]); o[3] = f2bf(a[3]);
    o[4] = f2bf(b[0]); o[5] = f2bf(b[1]); o[6] = f2bf(b[2]); o[7] = f2bf(b[3]);
    *(ushort8*)(out + i * 8) = o;
  }
}

// ---------------- router: fp32 logits, softmax, top-2 ----------------------
__global__ __launch_bounds__(64) void router_kernel(const float* __restrict__ x,
                                                    const float* __restrict__ rw,
                                                    int* __restrict__ tokexp,
                                                    float* __restrict__ tokwt,
                                                    int* __restrict__ counts) {
  int t = blockIdx.x, lane = threadIdx.x;
  const float* xrow = x + (size_t)t * HID;
  float xr[32];
#pragma unroll
  for (int i = 0; i < 32; i++) xr[i] = xrow[lane + 64 * i];
  float lg[NEXP];
#pragma unroll
  for (int e = 0; e < NEXP; e++) {
    const float* r = rw + e * HID;
    float d = 0.f;
#pragma unroll
    for (int i = 0; i < 32; i++) d = fmaf(xr[i], r[lane + 64 * i], d);
#pragma unroll
    for (int s = 32; s; s >>= 1) d += __shfl_xor(d, s);
    lg[e] = d;
  }
  if (lane == 0) {
    float mx = lg[0];
    for (int e = 1; e < NEXP; e++) mx = fmaxf(mx, lg[e]);
    float p[NEXP], sum = 0.f;
    for (int e = 0; e < NEXP; e++) { p[e] = expf(lg[e] - mx); sum += p[e]; }
    int e0 = 0; float b0 = p[0];
    for (int e = 1; e < NEXP; e++) if (p[e] > b0) { b0 = p[e]; e0 = e; }
    int e1 = -1; float b1 = -1.f;
    for (int e = 0; e < NEXP; e++) if (e != e0 && p[e] > b1) { b1 = p[e]; e1 = e; }
    float inv = 1.f / sum;
    tokexp[2 * t] = e0; tokexp[2 * t + 1] = e1;
    tokwt[2 * t] = b0 * inv; tokwt[2 * t + 1] = b1 * inv;
    atomicAdd(&counts[e0], 1);
    atomicAdd(&counts[e1], 1);
  }
}

// ---------------- scan + placement -----------------------------------------
__global__ void scan_kernel(const int* __restrict__ counts, int* __restrict__ offsets,
                            int* __restrict__ cursors) {
  if (threadIdx.x == 0) {
    int acc = 0;
    for (int e = 0; e < NEXP; e++) { offsets[e] = acc; cursors[e] = acc; acc += counts[e]; }
  }
}

__global__ __launch_bounds__(256) void place_kernel(const int* __restrict__ tokexp,
                                                    const float* __restrict__ tokwt,
                                                    int* __restrict__ cursors,
                                                    int* __restrict__ rowtok,
                                                    float* __restrict__ rowwt) {
  int a = blockIdx.x * 256 + threadIdx.x;
  if (a >= 2 * T_TOK) return;
  int e = tokexp[a];
  int pos = atomicAdd(&cursors[e], 1);
  rowtok[pos] = a >> 1;
  rowwt[pos] = tokwt[a];
}

// ---------------- GEMM1: h = silu(x@Wg^T) * (x@Wu^T), gathered rows --------
// 512 thr / 8 waves. Waves 0-3: gate acc for the 128x128 tile; waves 4-7: up.
// BK=64: LDS row = 128B = 8 x 16B chunks; swizzle chunk ^= (row&7).
__global__ __launch_bounds__(512, 2) void gemm1_kernel(
    const unsigned short* __restrict__ xb, const unsigned short* __restrict__ w1b,
    unsigned short* __restrict__ hbuf, const int* __restrict__ rowtok,
    const int* __restrict__ counts, const int* __restrict__ offsets) {
  int e = blockIdx.z;
  int cnt = counts[e];
  int m0 = blockIdx.x * 128;
  if (m0 >= cnt) return;
  int n0 = blockIdx.y * 128;
  int off = offsets[e];

  __shared__ __attribute__((aligned(64))) char smem[49664];
  unsigned short* sA  = (unsigned short*)smem;          // 16 KB
  unsigned short* sBg = sA + 8192;                      // 16 KB
  unsigned short* sBu = sBg + 8192;                     // 16 KB
  unsigned int*   stok = (unsigned int*)(smem + 49152); // 512 B

  int tid = threadIdx.x;
  if (tid < 128) {
    int r = m0 + tid; if (r > cnt - 1) r = cnt - 1;
    stok[tid] = (unsigned)rowtok[off + r] * (HID * 2);
  }
  __syncthreads();

  // staging: 1024 x 16B slots per matrix; thread owns slots tid, tid+512.
  // slot -> row = slot>>3, chunk = slot&7; global chunk = chunk ^ (row&7).
  unsigned aoff[2], boff[2];
#pragma unroll
  for (int j = 0; j < 2; j++) {
    int r = (tid >> 3) + 64 * j;
    int c = (tid & 7) ^ (r & 7);
    aoff[j] = stok[r] + c * 16;
    boff[j] = (unsigned)(n0 + r) * (HID * 2) + c * 16;
  }
  const char* xc  = (const char*)xb;
  const char* w1g = (const char*)w1b + (size_t)e * (2 * INTER) * HID * 2;
  const char* w1u = w1g + (size_t)INTER * HID * 2;
  char* lA = (char*)sA  + tid * 16;
  char* lG = (char*)sBg + tid * 16;
  char* lU = (char*)sBu + tid * 16;

  int lane = tid & 63, wid = tid >> 6;
  int wid2 = wid & 3;
  int wrow = (wid2 >> 1) * 64, wcol = (wid2 & 1) * 64;
  bool isGate = wid < 4;
  const unsigned short* sB = isGate ? sBg : sBu;
  int fr = lane & 15, fq = lane >> 4;
  int sw = fr & 7;
  int c0 = (fq ^ sw) * 8;
  int c1 = ((fq + 4) ^ sw) * 8;

  f32x4 acc[4][4] = {};

  for (int kb = 0; kb < HID * 2; kb += 128) {
    gload16(xc  + aoff[0] + kb, lA);  gload16(xc  + aoff[1] + kb, lA + 8192);
    gload16(w1g + boff[0] + kb, lG);  gload16(w1g + boff[1] + kb, lG + 8192);
    gload16(w1u + boff[0] + kb, lU);  gload16(w1u + boff[1] + kb, lU + 8192);
    __syncthreads();   // compiler drains vmcnt before s_barrier
#pragma unroll
    for (int kk2 = 0; kk2 < 2; kk2++) {
      int co = kk2 ? c1 : c0;
      bf16x8 a[4];
#pragma unroll
      for (int m = 0; m < 4; m++)
        a[m] = *(const bf16x8*)(sA + (wrow + m * 16 + fr) * 64 + co);
#pragma unroll
      for (int n = 0; n < 4; n++) {
        bf16x8 b = *(const bf16x8*)(sB + (wcol + n * 16 + fr) * 64 + co);
#pragma unroll
        for (int m = 0; m < 4; m++)
          acc[m][n] = __builtin_amdgcn_mfma_f32_16x16x32_bf16(a[m], b, acc[m][n], 0, 0, 0);
      }
    }
    __syncthreads();
  }

  // Epilogue: gate waves ship gate fragments through LDS scratch (32KB,
  // overlays sA/sBg); up waves (identical wid2 -> identical lane/reg map)
  // read pointwise, compute h = up * silu(gate), store bf16.
  // Region g: byte = g*8192 + lane*128 + ((m*2+nn)^(lane&7))*16.
#pragma unroll
  for (int t = 0; t < 2; t++) {
    if (isGate) {
#pragma unroll
      for (int m = 0; m < 4; m++)
#pragma unroll
        for (int nn = 0; nn < 2; nn++)
          *(f32x4*)(smem + wid2 * 8192 + lane * 128 + (((m * 2 + nn) ^ sw) * 16)) =
              acc[m][2 * t + nn];
    }
    __syncthreads();
    if (!isGate) {
#pragma unroll
      for (int m = 0; m < 4; m++) {
#pragma unroll
        for (int nn = 0; nn < 2; nn++) {
          f32x4 g4 = *(const f32x4*)(smem + wid2 * 8192 + lane * 128 +
                                     (((m * 2 + nn) ^ sw) * 16));
          int n = 2 * t + nn;
#pragma unroll
          for (int r = 0; r < 4; r++) {
            int grow = m0 + wrow + m * 16 + fq * 4 + r;
            if (grow >= cnt) continue;
            float g = g4[r];
            float u = acc[m][n][r];
            float hv = u * g / (1.f + __expf(-g));
            hbuf[(size_t)(off + grow) * INTER + n0 + wcol + n * 16 + fr] = f2bf(hv);
          }
        }
      }
    }
    __syncthreads();
  }
}

// ---------------- GEMM2: out[tok] += wt * (h @ W2^T) -----------------------
__global__ __launch_bounds__(256) void gemm2_kernel(
    const unsigned short* __restrict__ hbuf, const unsigned short* __restrict__ w2b,
    const int* __restrict__ rowtok, const float* __restrict__ rowwt,
    const int* __restrict__ counts, const int* __restrict__ offsets,
    float* __restrict__ out) {
  int e = blockIdx.z;
  int cnt = counts[e];
  int m0 = blockIdx.x * 128;
  if (m0 >= cnt) return;
  int n0 = blockIdx.y * 128;
  int off = offsets[e];

  __shared__ unsigned short sA[128 * 64];
  __shared__ unsigned short sB[128 * 64];

  int tid = threadIdx.x;
  int srow0 = tid >> 3;
  int schunk = tid & 7;
  unsigned aoff[4], boff[4];
#pragma unroll
  for (int j = 0; j < 4; j++) {
    int r = srow0 + 32 * j;
    int c = schunk ^ (r & 7);
    int ar = m0 + r; if (ar > cnt - 1) ar = cnt - 1;
    aoff[j] = (unsigned)(off + ar) * (INTER * 2) + c * 16;
    boff[j] = (unsigned)(n0 + r) * (INTER * 2) + c * 16;
  }
  const char* hc  = (const char*)hbuf;
  const char* w2e = (const char*)w2b + (size_t)e * HID * INTER * 2;
  char* lA = (char*)sA + tid * 16;
  char* lB = (char*)sB + tid * 16;

  int lane = tid & 63, wid = tid >> 6;
  int wrow = (wid >> 1) * 64, wcol = (wid & 1) * 64;
  int fr = lane & 15, fq = lane >> 4;
  int sw = fr & 7;
  int c0 = (fq ^ sw) * 8;
  int c1 = ((fq + 4) ^ sw) * 8;

  f32x4 acc[4][4] = {};

  for (int kb = 0; kb < INTER * 2; kb += 128) {
#pragma unroll
    for (int j = 0; j < 4; j++) gload16(hc  + aoff[j] + kb, lA + j * 4096);
#pragma unroll
    for (int j = 0; j < 4; j++) gload16(w2e + boff[j] + kb, lB + j * 4096);
    __syncthreads();
#pragma unroll
    for (int kk2 = 0; kk2 < 2; kk2++) {
      int co = kk2 ? c1 : c0;
      bf16x8 a[4];
#pragma unroll
      for (int m = 0; m < 4; m++)
        a[m] = *(const bf16x8*)(sA + (wrow + m * 16 + fr) * 64 + co);
#pragma unroll
      for (int n = 0; n < 4; n++) {
        bf16x8 b = *(const bf16x8*)(sB + (wcol + n * 16 + fr) * 64 + co);
#pragma unroll
        for (int m = 0; m < 4; m++)
          acc[m][n] = __builtin_amdgcn_mfma_f32_16x16x32_bf16(a[m], b, acc[m][n], 0, 0, 0);
      }
    }
    __syncthreads();
  }

#pragma unroll
  for (int m = 0; m < 4; m++) {
#pragma unroll
    for (int r = 0; r < 4; r++) {
      int grow = m0 + wrow + m * 16 + fq * 4 + r;
      if (grow >= cnt) continue;
      int tok = rowtok[off + grow];
      float wt = rowwt[off + grow];
      float* orow = out + (size_t)tok * HID + n0 + wcol;
#pragma unroll
      for (int n = 0; n < 4; n++)
        atomicAdd(orow + n * 16 + fr, acc[m][n][r] * wt);
    }
  }
}

// ---------------- host launch ----------------------------------------------
extern "C" void kernel_launch(void* const* d_in, const int* in_sizes, int n_in,
                              void* d_out, int out_size, void* d_ws, size_t ws_size,
                              hipStream_t stream) {
  const float* x  = (const float*)d_in[0];
  const float* w1 = (const float*)d_in[1];
  const float* w2 = (const float*)d_in[2];
  const float* rw = (const float*)d_in[3];

  char* ws = (char*)d_ws;
  size_t o = 0;
  auto alloc = [&](size_t bytes) {
    char* p = ws + o;
    o += (bytes + 255) & ~(size_t)255;
    return p;
  };
  unsigned short* xb   = (unsigned short*)alloc((size_t)T_TOK * HID * 2);
  unsigned short* w1b  = (unsigned short*)alloc((size_t)NEXP * 2 * INTER * HID * 2);
  unsigned short* w2b  = (unsigned short*)alloc((size_t)NEXP * HID * INTER * 2);
  unsigned short* hbuf = (unsigned short*)alloc((size_t)CAP * INTER * 2);
  int*   rowtok = (int*)alloc((size_t)CAP * 4);
  float* rowwt  = (float*)alloc((size_t)CAP * 4);
  int*   tokexp = (int*)alloc((size_t)2 * T_TOK * 4);
  float* tokwt  = (float*)alloc((size_t)2 * T_TOK * 4);
  int*   ctrl   = (int*)alloc(32 * 4);
  int* counts = ctrl; int* offsets = ctrl + 8; int* cursors = ctrl + 16;
  if (o > ws_size) return;  // ws too small: bail cleanly (output stays poisoned)

  hipMemsetAsync(ctrl, 0, 32 * 4, stream);
  hipMemsetAsync(d_out, 0, (size_t)out_size * 4, stream);

  cvt_kernel<<<2048, 256, 0, stream>>>(x,  xb,  (long)T_TOK * HID / 8);
  cvt_kernel<<<4096, 256, 0, stream>>>(w1, w1b, (long)NEXP * 2 * INTER * HID / 8);
  cvt_kernel<<<4096, 256, 0, stream>>>(w2, w2b, (long)NEXP * HID * INTER / 8);

  router_kernel<<<T_TOK, 64, 0, stream>>>(x, rw, tokexp, tokwt, counts);
  scan_kernel<<<1, 64, 0, stream>>>(counts, offsets, cursors);
  place_kernel<<<(2 * T_TOK) / 256, 256, 0, stream>>>(tokexp, tokwt, cursors, rowtok, rowwt);

  gemm1_kernel<<<dim3(T_TOK / 128, INTER / 128, NEXP), 512, 0, stream>>>(
      xb, w1b, hbuf, rowtok, counts, offsets);
  gemm2_kernel<<<dim3(T_TOK / 128, HID / 128, NEXP), 256, 0, stream>>>(
      hbuf, w2b, rowtok, rowwt, counts, offsets, (float*)d_out);
}